// Round 6
// baseline (344.808 us; speedup 1.0000x reference)
//
#include <hip/hip_runtime.h>
#include <cstdint>

// Problem constants
#define U_UNITS 64
#define M_SLOTS 8192
#define D_DIM   64
#define SCH     32                // split-K chunks per unit (grid = U*SCH = 2048)
#define CHUNK   (M_SLOTS / SCH)   // 256 slots per chunk
#define BLK     256
#define SPG     4                 // slots per 16-lane group per iteration

typedef __attribute__((ext_vector_type(4))) float fvec4;

// ---------------------------------------------------------------------------
// Kernel A (fused): MAIN LOOP IS PURE-READ. The memories pass-through copy is
// moved to a tail loop so no store sits in the load-use vmcnt chain:
//   main loop: load atts + mem float4s (read-only), dot + online softmax + PV.
//              Only store: one float4 of staged scores per 16-lane group.
//   tail loop: re-read mem (L3-warm: it was just read) and stream to out_m
//              with NON-TEMPORAL stores -> pure store stream, fill-like BW,
//              zero load-use waits.
// Theory under test: interleaved stores serialize via the vmcnt FIFO (all
// prior rounds plateaued at 2.2-2.4 TB/s regardless of occupancy/ILP).
// ---------------------------------------------------------------------------
__global__ __launch_bounds__(BLK, 4) void fused_kernel(
    const float* __restrict__ att,    // [U][D]
    const float* __restrict__ atts,   // [U][M][D]
    const float* __restrict__ tmpr,   // [U]
    const int*   __restrict__ mask,   // [U][M] (nonzero -> dropped)
    const float* __restrict__ mem,    // [U][M][D]
    float* __restrict__ out_w,        // [U][M]  staged raw scores (wfix finalizes)
    float* __restrict__ out_m,        // [U][M][D] pass-through copy
    float* __restrict__ pmax,         // [U*SCH]
    float* __restrict__ psum,         // [U*SCH]
    float* __restrict__ pout)         // [U*SCH][D] unnormalized PV partials
{
    const int b = blockIdx.x;
    const int u = b / SCH, c = b % SCH;
    const int tid = threadIdx.x;

    __shared__ float s_att[D_DIM];
    __shared__ int   s_mask[CHUNK];
    __shared__ float s_m[4], s_s[4];
    __shared__ float s_acc[4 * D_DIM];

    if (tid < D_DIM) s_att[tid] = att[u * D_DIM + tid];
    if (tid < CHUNK / 4)
        ((int4*)s_mask)[tid] = ((const int4*)(mask + (size_t)u * M_SLOTS + c * CHUNK))[tid];
    __syncthreads();

    const int grp = tid >> 4;             // 16 groups; each owns 4 slots/iter
    const int r   = tid & 15;
    const int cg  = r * 4;                // column-group start (4 floats)
    const float a0 = s_att[cg], a1 = s_att[cg + 1];
    const float a2 = s_att[cg + 2], a3 = s_att[cg + 3];
    const float invt = 1.0f / tmpr[u];

    const size_t ubase = (size_t)u * M_SLOTS * D_DIM + (size_t)c * CHUNK * D_DIM;
    const float* __restrict__ abase = atts + ubase;
    const float* __restrict__ mbase = mem + ubase;

    float m = -1e30f, sm = 0.f;
    float acc0 = 0.f, acc1 = 0.f, acc2 = 0.f, acc3 = 0.f;

    #pragma unroll
    for (int k = 0; k < CHUNK / (16 * SPG); ++k) {      // 4 iterations
        const int sl0 = k * 64 + grp * SPG;             // 4 consecutive slots

        // ---- issue all 8 loads back-to-back (independent addresses) ----
        float4 va[SPG], vm[SPG];
        #pragma unroll
        for (int i = 0; i < SPG; ++i)
            va[i] = *(const float4*)(abase + (size_t)(sl0 + i) * D_DIM + cg);
        #pragma unroll
        for (int i = 0; i < SPG; ++i)
            vm[i] = *(const float4*)(mbase + (size_t)(sl0 + i) * D_DIM + cg);

        // ---- 4 dot products, pipelined shfl chains ----
        float wv[SPG];
        #pragma unroll
        for (int i = 0; i < SPG; ++i) {
            float d = va[i].x * a0 + va[i].y * a1 + va[i].z * a2 + va[i].w * a3;
            d += __shfl_xor(d, 1);
            d += __shfl_xor(d, 2);
            d += __shfl_xor(d, 4);
            d += __shfl_xor(d, 8);
            wv[i] = s_mask[sl0 + i] ? -1e30f : d * invt;
        }

        // coalesced score stage: one float4 per group (tiny, 2 MB total)
        if (r == 0)
            *(float4*)(out_w + (size_t)u * M_SLOTS + c * CHUNK + sl0) =
                make_float4(wv[0], wv[1], wv[2], wv[3]);

        // ---- ONE online-softmax update for 4 slots ----
        const float mx4  = fmaxf(fmaxf(wv[0], wv[1]), fmaxf(wv[2], wv[3]));
        const float newm = fmaxf(m, mx4);
        const float scf  = __expf(m - newm);     // 1.0 when max unchanged
        float e[SPG];
        #pragma unroll
        for (int i = 0; i < SPG; ++i) e[i] = __expf(wv[i] - newm);
        acc0 = acc0 * scf + e[0] * vm[0].x + e[1] * vm[1].x + e[2] * vm[2].x + e[3] * vm[3].x;
        acc1 = acc1 * scf + e[0] * vm[0].y + e[1] * vm[1].y + e[2] * vm[2].y + e[3] * vm[3].y;
        acc2 = acc2 * scf + e[0] * vm[0].z + e[1] * vm[1].z + e[2] * vm[2].z + e[3] * vm[3].z;
        acc3 = acc3 * scf + e[0] * vm[0].w + e[1] * vm[1].w + e[2] * vm[2].w + e[3] * vm[3].w;
        sm   = sm * scf + (e[0] + e[1]) + (e[2] + e[3]);
        m    = newm;
    }

    // ---- combine the 4 groups within each wave (xor bits 4,5) ----
    float wm = m;
    wm = fmaxf(wm, __shfl_xor(wm, 16));
    wm = fmaxf(wm, __shfl_xor(wm, 32));
    const float f = __expf(m - wm);
    float acc[4] = {acc0 * f, acc1 * f, acc2 * f, acc3 * f};
    sm *= f;
    #pragma unroll
    for (int j = 0; j < 4; ++j) {
        acc[j] += __shfl_xor(acc[j], 16);
        acc[j] += __shfl_xor(acc[j], 32);
    }
    sm += __shfl_xor(sm, 16);
    sm += __shfl_xor(sm, 32);

    // ---- combine the 4 waves via LDS ----
    const int lane = tid & 63, w = tid >> 6;
    if (lane == 0) s_m[w] = wm;
    __syncthreads();
    const float bmx = fmaxf(fmaxf(s_m[0], s_m[1]), fmaxf(s_m[2], s_m[3]));
    const float f2  = __expf(wm - bmx);
    if (lane == 0) s_s[w] = sm * f2;
    if (lane < 16) {
        #pragma unroll
        for (int j = 0; j < 4; ++j) s_acc[w * D_DIM + lane * 4 + j] = acc[j] * f2;
    }
    __syncthreads();
    if (tid < D_DIM) {
        const float s = s_acc[tid] + s_acc[D_DIM + tid]
                      + s_acc[2 * D_DIM + tid] + s_acc[3 * D_DIM + tid];
        pout[(size_t)b * D_DIM + tid] = s;
    }
    if (tid == 0) {
        pmax[b] = bmx;
        psum[b] = s_s[0] + s_s[1] + s_s[2] + s_s[3];   // group-uniform sm: no over-count
    }

    // ---- tail: memories pass-through copy (pure store stream) ----
    // Re-read mem (just read above -> L3-warm), write non-temporal. 4096
    // float4 per block, 256 threads -> 16 fully coalesced sweeps, no
    // load-use dependency chains beyond each sweep's own load.
    const fvec4* __restrict__ msrc = (const fvec4*)mbase;
    fvec4* __restrict__ mdst = (fvec4*)(out_m + ubase);
    #pragma unroll
    for (int j = 0; j < (CHUNK * D_DIM / 4) / BLK; ++j) {
        const fvec4 v = msrc[tid + j * BLK];
        __builtin_nontemporal_store(v, &mdst[tid + j * BLK]);
    }
}

// ---------------------------------------------------------------------------
// Kernel B: per-unit global stats + final outputs.
// grid = U blocks x D threads.
// ---------------------------------------------------------------------------
__global__ void combine_out_kernel(
    const float* __restrict__ pmax,
    const float* __restrict__ psum,
    const float* __restrict__ pout,
    float* __restrict__ gmx,          // [U]
    float* __restrict__ ginv,         // [U]
    float* __restrict__ out_o)        // [U][D]
{
    const int u = blockIdx.x, t = threadIdx.x;
    float mx = -1e30f;
    #pragma unroll
    for (int c = 0; c < SCH; ++c) mx = fmaxf(mx, pmax[u * SCH + c]);
    float s = 0.f;
    #pragma unroll
    for (int c = 0; c < SCH; ++c) s += psum[u * SCH + c] * __expf(pmax[u * SCH + c] - mx);
    const float inv = 1.0f / s;
    float o = 0.f;
    #pragma unroll
    for (int c = 0; c < SCH; ++c)
        o += __expf(pmax[u * SCH + c] - mx) * pout[((size_t)u * SCH + c) * D_DIM + t];
    out_o[u * D_DIM + t] = o * inv;
    if (t == 0) { gmx[u] = mx; ginv[u] = inv; }
}

// ---------------------------------------------------------------------------
// Kernel C: weights finalize in place: w = exp(sc - gmx[u]) * ginv[u].
// 4 MB traffic. One float4 per thread; grid = U*M/4/BLK = 512 blocks.
// Masked slots staged sc = -1e30 -> expf underflows to exactly 0.
// ---------------------------------------------------------------------------
__global__ __launch_bounds__(BLK) void wfix_kernel(
    const float* __restrict__ gmx,
    const float* __restrict__ ginv,
    float* __restrict__ out_w)
{
    const int g = blockIdx.x * BLK + threadIdx.x;   // float4 index, U*M/4 total
    const int u = g >> 11;                          // 2048 float4 per unit
    const float a = gmx[u], gi = ginv[u];
    float4* p = reinterpret_cast<float4*>(out_w) + g;
    float4 v = *p;
    v.x = __expf(v.x - a) * gi;
    v.y = __expf(v.y - a) * gi;
    v.z = __expf(v.z - a) * gi;
    v.w = __expf(v.w - a) * gi;
    *p = v;
}

extern "C" void kernel_launch(void* const* d_in, const int* in_sizes, int n_in,
                              void* d_out, int out_size, void* d_ws, size_t ws_size,
                              hipStream_t stream)
{
    const float* att  = (const float*)d_in[0];  // attention  [64,64]
    const float* atts = (const float*)d_in[1];  // attentions [64,8192,64]
    const float* mem  = (const float*)d_in[2];  // memories   [64,8192,64]
    const float* tmpr = (const float*)d_in[3];  // tmpr       [64,1]
    const int*   mask = (const int*)d_in[4];    // mask       [64,8192]

    float* out   = (float*)d_out;
    float* out_o = out;                                   // outputs  [64,64]
    float* out_w = out + U_UNITS * D_DIM;                 // weights  [64,8192]
    float* out_m = out_w + (size_t)U_UNITS * M_SLOTS;     // memories [64,8192,64]

    float* ws    = (float*)d_ws;
    float* pmax  = ws;                                // U*SCH
    float* psum  = pmax + U_UNITS * SCH;              // U*SCH
    float* gmx   = psum + U_UNITS * SCH;              // U
    float* ginv  = gmx + U_UNITS;                     // U
    float* pout  = ginv + U_UNITS;                    // U*SCH*D

    fused_kernel<<<U_UNITS * SCH, BLK, 0, stream>>>(
        att, atts, tmpr, mask, mem, out_w, out_m, pmax, psum, pout);
    combine_out_kernel<<<U_UNITS, D_DIM, 0, stream>>>(pmax, psum, pout, gmx, ginv, out_o);
    wfix_kernel<<<(U_UNITS * M_SLOTS / 4) / BLK, BLK, 0, stream>>>(gmx, ginv, out_w);
}

// Round 7
// 337.131 us; speedup vs baseline: 1.0228x; 1.0228x over previous
//
#include <hip/hip_runtime.h>
#include <cstdint>

// Problem constants
#define U_UNITS 64
#define M_SLOTS 8192
#define D_DIM   64
#define SCH     32                // split-K chunks per unit (grid = U*SCH = 2048)
#define CHUNK   (M_SLOTS / SCH)   // 256 slots per chunk
#define BLK     256
#define SPG     4                 // slots per 16-lane group per iteration

typedef __attribute__((ext_vector_type(4))) float fvec4;

// ---------------------------------------------------------------------------
// ABLATION ROUND: split the fused kernel into its two memory streams so
// rocprof times each separately.
//
// Kernel 1 (score): reads ONLY attentions (128 MB) + tiny mask/att; computes
// dot + shfl-reduce + online (max,sum) stats; writes raw scores (2 MB) and
// per-chunk pmax/psum. If this plateaus at ~2.4 TB/s the dot/shfl structure
// is the bottleneck; if it streams, it isn't.
// ---------------------------------------------------------------------------
__global__ __launch_bounds__(BLK) void score_kernel(
    const float* __restrict__ att,    // [U][D]
    const float* __restrict__ atts,   // [U][M][D]
    const float* __restrict__ tmpr,   // [U]
    const int*   __restrict__ mask,   // [U][M] (nonzero -> dropped)
    float* __restrict__ out_w,        // [U][M] staged raw scores
    float* __restrict__ pmax,         // [U*SCH]
    float* __restrict__ psum)         // [U*SCH]
{
    const int b = blockIdx.x;
    const int u = b / SCH, c = b % SCH;
    const int tid = threadIdx.x;
    const int grp = tid >> 4, r = tid & 15, cg = r * 4;

    __shared__ float s_m[4], s_s[4];

    // per-lane slice of the query vector (same 16B for all groups; L1-served)
    const float4 av = *(const float4*)(att + u * D_DIM + cg);
    const float invt = 1.0f / tmpr[u];

    const size_t ubase = (size_t)u * M_SLOTS * D_DIM + (size_t)c * CHUNK * D_DIM;
    const float* __restrict__ abase = atts + ubase;
    const int*   __restrict__ mkbase = mask + (size_t)u * M_SLOTS + c * CHUNK;
    float* __restrict__ swbase = out_w + (size_t)u * M_SLOTS + c * CHUNK;

    float m = -1e30f, sm = 0.f;

    #pragma unroll
    for (int k = 0; k < CHUNK / (16 * SPG); ++k) {      // 4 iterations
        const int sl0 = k * 64 + grp * SPG;
        float4 va[SPG];
        #pragma unroll
        for (int i = 0; i < SPG; ++i)
            va[i] = *(const float4*)(abase + (size_t)(sl0 + i) * D_DIM + cg);
        const int4 mk = *(const int4*)(mkbase + sl0);   // group-uniform broadcast

        float wv[SPG];
        #pragma unroll
        for (int i = 0; i < SPG; ++i) {
            float d = va[i].x * av.x + va[i].y * av.y + va[i].z * av.z + va[i].w * av.w;
            d += __shfl_xor(d, 1);
            d += __shfl_xor(d, 2);
            d += __shfl_xor(d, 4);
            d += __shfl_xor(d, 8);
            wv[i] = d * invt;
        }
        if (mk.x) wv[0] = -1e30f;
        if (mk.y) wv[1] = -1e30f;
        if (mk.z) wv[2] = -1e30f;
        if (mk.w) wv[3] = -1e30f;

        if (r == 0)
            *(float4*)(swbase + sl0) = make_float4(wv[0], wv[1], wv[2], wv[3]);

        // online (max,sum) update, one rescale per 4 slots
        const float mx4  = fmaxf(fmaxf(wv[0], wv[1]), fmaxf(wv[2], wv[3]));
        const float newm = fmaxf(m, mx4);
        const float scf  = __expf(m - newm);
        sm = sm * scf + __expf(wv[0] - newm) + __expf(wv[1] - newm)
                      + __expf(wv[2] - newm) + __expf(wv[3] - newm);
        m = newm;
    }

    // merge (m,sm) across the 4 groups of the wave (values group-uniform)
    #pragma unroll
    for (int off = 16; off <= 32; off <<= 1) {
        const float om = __shfl_xor(m, off);
        const float os = __shfl_xor(sm, off);
        const float nm = fmaxf(m, om);
        sm = sm * __expf(m - nm) + os * __expf(om - nm);
        m = nm;
    }
    // merge across the 4 waves via LDS
    const int lane = tid & 63, w = tid >> 6;
    if (lane == 0) { s_m[w] = m; s_s[w] = sm; }
    __syncthreads();
    if (tid == 0) {
        float bm = fmaxf(fmaxf(s_m[0], s_m[1]), fmaxf(s_m[2], s_m[3]));
        float bs = s_s[0] * __expf(s_m[0] - bm) + s_s[1] * __expf(s_m[1] - bm)
                 + s_s[2] * __expf(s_m[2] - bm) + s_s[3] * __expf(s_m[3] - bm);
        pmax[b] = bm;
        psum[b] = bs;
    }
}

// ---------------------------------------------------------------------------
// Kernel 2: per-unit global stats. grid = 1 x 64.
// ---------------------------------------------------------------------------
__global__ void combine_kernel(
    const float* __restrict__ pmax, const float* __restrict__ psum,
    float* __restrict__ gmx, float* __restrict__ ginv)
{
    const int u = threadIdx.x;
    float mx = -1e30f;
    #pragma unroll
    for (int c = 0; c < SCH; ++c) mx = fmaxf(mx, pmax[u * SCH + c]);
    float s = 0.f;
    #pragma unroll
    for (int c = 0; c < SCH; ++c) s += psum[u * SCH + c] * __expf(pmax[u * SCH + c] - mx);
    gmx[u] = mx;
    ginv[u] = 1.0f / s;
}

// ---------------------------------------------------------------------------
// Kernel 3 (pv): maximally copy-like. NO LDS / shfl / mask in the loop:
//   broadcast-load 4 staged scores (group-uniform address),
//   4 memories float4 loads, 4 non-temporal out_m stores,
//   finalize weights in-register (exp redundantly per lane, VALU is idle),
//   accumulate normalized PV. Weights written back in place (wfix folded in).
// Structurally the m13 6.3 TB/s copy loop + FMAs.
// ---------------------------------------------------------------------------
__global__ __launch_bounds__(BLK) void pv_kernel(
    const float* __restrict__ mem,    // [U][M][D]
    const float* __restrict__ gmx,
    const float* __restrict__ ginv,
    float* __restrict__ out_w,        // [U][M] read staged score, write weight
    float* __restrict__ out_m,        // [U][M][D]
    float* __restrict__ pout)         // [U*SCH][D] normalized PV partials
{
    const int b = blockIdx.x;
    const int u = b / SCH, c = b % SCH;
    const int tid = threadIdx.x;
    const int grp = tid >> 4, r = tid & 15, cg = r * 4;
    const float gm = gmx[u], gi = ginv[u];

    __shared__ float s_acc[4 * D_DIM];

    const size_t ubase = (size_t)u * M_SLOTS * D_DIM + (size_t)c * CHUNK * D_DIM;
    const float* __restrict__ mbase = mem + ubase;
    float* __restrict__ obase = out_m + ubase;
    float* __restrict__ swbase = out_w + (size_t)u * M_SLOTS + c * CHUNK;

    float acc0 = 0.f, acc1 = 0.f, acc2 = 0.f, acc3 = 0.f;

    #pragma unroll
    for (int k = 0; k < CHUNK / (16 * SPG); ++k) {      // 4 iterations
        const int sl0 = k * 64 + grp * SPG;

        const float4 ws = *(const float4*)(swbase + sl0);   // broadcast in group
        float4 vm[SPG];
        #pragma unroll
        for (int i = 0; i < SPG; ++i)
            vm[i] = *(const float4*)(mbase + (size_t)(sl0 + i) * D_DIM + cg);

        const float w0 = __expf(ws.x - gm) * gi;   // masked: -1e30 -> exactly 0
        const float w1 = __expf(ws.y - gm) * gi;
        const float w2 = __expf(ws.z - gm) * gi;
        const float w3 = __expf(ws.w - gm) * gi;

        #pragma unroll
        for (int i = 0; i < SPG; ++i)
            __builtin_nontemporal_store(
                *(const fvec4*)&vm[i],
                (fvec4*)(obase + (size_t)(sl0 + i) * D_DIM + cg));

        acc0 += w0 * vm[0].x + w1 * vm[1].x + w2 * vm[2].x + w3 * vm[3].x;
        acc1 += w0 * vm[0].y + w1 * vm[1].y + w2 * vm[2].y + w3 * vm[3].y;
        acc2 += w0 * vm[0].z + w1 * vm[1].z + w2 * vm[2].z + w3 * vm[3].z;
        acc3 += w0 * vm[0].w + w1 * vm[1].w + w2 * vm[2].w + w3 * vm[3].w;

        if (r == 0)
            *(float4*)(swbase + sl0) = make_float4(w0, w1, w2, w3);  // final weights
    }

    // reduce PV across the 4 groups of each wave (group-uniform weights ->
    // lane-distinct partials only across groups: xor bits 4,5)
    float acc[4] = {acc0, acc1, acc2, acc3};
    #pragma unroll
    for (int j = 0; j < 4; ++j) {
        acc[j] += __shfl_xor(acc[j], 16);
        acc[j] += __shfl_xor(acc[j], 32);
    }
    const int lane = tid & 63, w = tid >> 6;
    if (lane < 16) {
        #pragma unroll
        for (int j = 0; j < 4; ++j) s_acc[w * D_DIM + lane * 4 + j] = acc[j];
    }
    __syncthreads();
    if (tid < D_DIM) {
        const float s = s_acc[tid] + s_acc[D_DIM + tid]
                      + s_acc[2 * D_DIM + tid] + s_acc[3 * D_DIM + tid];
        pout[(size_t)b * D_DIM + tid] = s;
    }
}

// ---------------------------------------------------------------------------
// Kernel 4: reduce chunk partials (already normalized) -> outputs [U][D].
// ---------------------------------------------------------------------------
__global__ void out_kernel(const float* __restrict__ pout, float* __restrict__ out_o)
{
    const int u = blockIdx.x, t = threadIdx.x;   // 64 x 64
    float s = 0.f;
    #pragma unroll
    for (int c = 0; c < SCH; ++c) s += pout[((size_t)u * SCH + c) * D_DIM + t];
    out_o[u * D_DIM + t] = s;
}

extern "C" void kernel_launch(void* const* d_in, const int* in_sizes, int n_in,
                              void* d_out, int out_size, void* d_ws, size_t ws_size,
                              hipStream_t stream)
{
    const float* att  = (const float*)d_in[0];  // attention  [64,64]
    const float* atts = (const float*)d_in[1];  // attentions [64,8192,64]
    const float* mem  = (const float*)d_in[2];  // memories   [64,8192,64]
    const float* tmpr = (const float*)d_in[3];  // tmpr       [64,1]
    const int*   mask = (const int*)d_in[4];    // mask       [64,8192]

    float* out   = (float*)d_out;
    float* out_o = out;                                   // outputs  [64,64]
    float* out_w = out + U_UNITS * D_DIM;                 // weights  [64,8192]
    float* out_m = out_w + (size_t)U_UNITS * M_SLOTS;     // memories [64,8192,64]

    float* ws    = (float*)d_ws;
    float* pmax  = ws;                                // U*SCH
    float* psum  = pmax + U_UNITS * SCH;              // U*SCH
    float* gmx   = psum + U_UNITS * SCH;              // U
    float* ginv  = gmx + U_UNITS;                     // U
    float* pout  = ginv + U_UNITS;                    // U*SCH*D

    score_kernel<<<U_UNITS * SCH, BLK, 0, stream>>>(att, atts, tmpr, mask, out_w, pmax, psum);
    combine_kernel<<<1, U_UNITS, 0, stream>>>(pmax, psum, gmx, ginv);
    pv_kernel<<<U_UNITS * SCH, BLK, 0, stream>>>(mem, gmx, ginv, out_w, out_m, pout);
    out_kernel<<<U_UNITS, D_DIM, 0, stream>>>(pout, out_o);
}

// Round 8
// 329.194 us; speedup vs baseline: 1.0474x; 1.0241x over previous
//
#include <hip/hip_runtime.h>
#include <cstdint>

// Problem constants
#define U_UNITS 64
#define M_SLOTS 8192
#define D_DIM   64
#define SCH     16                // softmax split-K chunks per unit
#define CHUNK   (M_SLOTS / SCH)   // 512 slots per chunk
#define BLK     256
#define WSLICE  8                 // finalize blocks per unit

// ---------------------------------------------------------------------------
// Kernel A: round-2 fused kernel VERBATIM (best measured through-cache rate,
// 3.6 TB/s): per (unit, chunk) block of 512 slots:
//   phase 1: scores -> LDS only, block-local max.
//   phase 2: we = exp(score - lmax); write UNNORMALIZED weights; accumulate
//            unnormalized PV partial; stream memories -> out_m copy.
//   emit pmax[b], psum[b], pout[b][:].
// ---------------------------------------------------------------------------
__global__ __launch_bounds__(BLK) void fused_kernel(
    const float* __restrict__ att,    // [U][D]
    const float* __restrict__ atts,   // [U][M][D]
    const float* __restrict__ tmpr,   // [U]
    const int*   __restrict__ mask,   // [U][M] (nonzero -> dropped)
    const float* __restrict__ mem,    // [U][M][D]
    float* __restrict__ out_w,        // [U][M]  (unnormalized until finalize)
    float* __restrict__ out_m,        // [U][M][D] pass-through copy
    float* __restrict__ pmax,         // [U*SCH]
    float* __restrict__ psum,         // [U*SCH]
    float* __restrict__ pout)         // [U*SCH][D] unnormalized PV partials
{
    const int b = blockIdx.x;
    const int u = b / SCH, c = b % SCH;
    const int tid = threadIdx.x;

    __shared__ float s_att[D_DIM];
    __shared__ float s_w[CHUNK];
    __shared__ float s_m[4], s_s[4];
    __shared__ float s_acc[4 * D_DIM];

    if (tid < D_DIM) s_att[tid] = att[u * D_DIM + tid];
    __syncthreads();

    const int cg = (tid & 15) * 4;        // column-group start (4 floats)
    const float a0 = s_att[cg], a1 = s_att[cg + 1];
    const float a2 = s_att[cg + 2], a3 = s_att[cg + 3];
    const float invt = 1.0f / tmpr[u];

    const size_t ubase = (size_t)u * M_SLOTS * D_DIM + (size_t)c * CHUNK * D_DIM;
    const float* __restrict__ abase = atts + ubase;

    // ---- phase 1: scores -> LDS, running max ----
    float lmx = -1e30f;
    #pragma unroll 4
    for (int k = 0; k < CHUNK / 16; ++k) {          // 32 iterations, 16 slots each
        const int sl = k * 16 + (tid >> 4);
        const float4 v = *(const float4*)(abase + (size_t)sl * D_DIM + cg);
        float d = v.x * a0 + v.y * a1 + v.z * a2 + v.w * a3;
        d += __shfl_xor(d, 1);
        d += __shfl_xor(d, 2);
        d += __shfl_xor(d, 4);
        d += __shfl_xor(d, 8);
        const float wv = mask[u * M_SLOTS + c * CHUNK + sl] ? -1e30f : d * invt;
        lmx = fmaxf(lmx, wv);
        if ((tid & 15) == 0) s_w[sl] = wv;
    }
    #pragma unroll
    for (int off = 1; off < 64; off <<= 1) lmx = fmaxf(lmx, __shfl_xor(lmx, off));
    if ((tid & 63) == 0) s_m[tid >> 6] = lmx;
    __syncthreads();                      // also publishes s_w
    const float mx = fmaxf(fmaxf(s_m[0], s_m[1]), fmaxf(s_m[2], s_m[3]));

    // ---- phase 2: exp once; weights out, PV accumulate, memories copy ----
    const float* __restrict__ mbase = mem + ubase;
    float* __restrict__ obase = out_m + ubase;
    float acc0 = 0.f, acc1 = 0.f, acc2 = 0.f, acc3 = 0.f;
    float sm = 0.f;                       // each slot counted 16x (broadcast), /16 later
    #pragma unroll 4
    for (int k = 0; k < CHUNK / 16; ++k) {
        const int sl = k * 16 + (tid >> 4);
        const float we = __expf(s_w[sl] - mx);      // LDS broadcast read
        const float4 v = *(const float4*)(mbase + (size_t)sl * D_DIM + cg);
        *(float4*)(obase + (size_t)sl * D_DIM + cg) = v;   // pass-through copy
        acc0 += we * v.x;
        acc1 += we * v.y;
        acc2 += we * v.z;
        acc3 += we * v.w;
        sm += we;
        if ((tid & 15) == 0)
            out_w[(size_t)u * M_SLOTS + c * CHUNK + sl] = we;  // unnormalized
    }

    // reduce PV across the 4 slot-subgroups within each wave (xor bits 4,5)
    float acc[4] = {acc0, acc1, acc2, acc3};
    #pragma unroll
    for (int j = 0; j < 4; ++j) {
        acc[j] += __shfl_xor(acc[j], 16);
        acc[j] += __shfl_xor(acc[j], 32);
    }
    // wave-reduce the exp-sum (64 lanes = 16x over-count)
    #pragma unroll
    for (int off = 1; off < 64; off <<= 1) sm += __shfl_xor(sm, off);

    const int lane = tid & 63, w = tid >> 6;
    if (lane == 0) s_s[w] = sm;
    if (lane < 16) {
        #pragma unroll
        for (int j = 0; j < 4; ++j) s_acc[w * D_DIM + lane * 4 + j] = acc[j];
    }
    __syncthreads();
    if (tid < D_DIM) {
        const float s = s_acc[tid] + s_acc[D_DIM + tid]
                      + s_acc[2 * D_DIM + tid] + s_acc[3 * D_DIM + tid];
        pout[(size_t)b * D_DIM + tid] = s;
    }
    if (tid == 0) {
        pmax[b] = mx;
        psum[b] = (s_s[0] + s_s[1] + s_s[2] + s_s[3]) * 0.0625f;  // /16, exact pow2
    }
}

// ---------------------------------------------------------------------------
// Kernel B: finalize = combine + wfix + out in ONE launch.
// grid = U*WSLICE = 512 blocks x 256 threads.
// Every block redundantly recomputes its unit's (gmax, 1/sum) from
// pmax/psum (64 B, L2-hit, ~50 cyc) -- cheaper than a serializing grid-1
// combine kernel + an extra dispatch gap.
//   - all blocks: scale a 1024-float slice of weights in place by
//     alpha_c = exp(pmax_c - gmax)/gsum  (float4 spans one chunk: 512%4==0)
//   - slice-0 blocks: outputs[u][:] from pout (SCH x D floats, L2-resident)
// ---------------------------------------------------------------------------
__global__ __launch_bounds__(BLK) void finalize_kernel(
    const float* __restrict__ pmax,   // [U*SCH]
    const float* __restrict__ psum,   // [U*SCH]
    const float* __restrict__ pout,   // [U*SCH][D]
    float* __restrict__ out_w,        // [U][M] in-place scale
    float* __restrict__ out_o)        // [U][D]
{
    const int b = blockIdx.x;
    const int u = b / WSLICE, slice = b % WSLICE;
    const int tid = threadIdx.x;

    // per-unit stats, redundantly per thread (values L2/L1-cached)
    float mx = -1e30f;
    #pragma unroll
    for (int c = 0; c < SCH; ++c) mx = fmaxf(mx, pmax[u * SCH + c]);
    float s = 0.f;
    #pragma unroll
    for (int c = 0; c < SCH; ++c) s += psum[u * SCH + c] * __expf(pmax[u * SCH + c] - mx);
    const float inv = 1.0f / s;

    // weights slice: unit has M/4 = 2048 float4; this block covers 256 of them
    const int idx4 = slice * BLK + tid;           // float4 index within unit
    const int c = idx4 >> 7;                      // 128 float4 per 512-slot chunk
    const float alpha = __expf(pmax[u * SCH + c] - mx) * inv;
    float4* p = reinterpret_cast<float4*>(out_w) + (size_t)u * (M_SLOTS / 4) + idx4;
    float4 v = *p;
    v.x *= alpha; v.y *= alpha; v.z *= alpha; v.w *= alpha;
    *p = v;

    // outputs: one slice per unit does it (64 threads active, 16-iter loop)
    if (slice == 0 && tid < D_DIM) {
        float o = 0.f;
        #pragma unroll
        for (int cc = 0; cc < SCH; ++cc)
            o += __expf(pmax[u * SCH + cc] - mx) * pout[((size_t)u * SCH + cc) * D_DIM + tid];
        out_o[u * D_DIM + tid] = o * inv;
    }
}

extern "C" void kernel_launch(void* const* d_in, const int* in_sizes, int n_in,
                              void* d_out, int out_size, void* d_ws, size_t ws_size,
                              hipStream_t stream)
{
    const float* att  = (const float*)d_in[0];  // attention  [64,64]
    const float* atts = (const float*)d_in[1];  // attentions [64,8192,64]
    const float* mem  = (const float*)d_in[2];  // memories   [64,8192,64]
    const float* tmpr = (const float*)d_in[3];  // tmpr       [64,1]
    const int*   mask = (const int*)d_in[4];    // mask       [64,8192]

    float* out   = (float*)d_out;
    float* out_o = out;                                   // outputs  [64,64]
    float* out_w = out + U_UNITS * D_DIM;                 // weights  [64,8192]
    float* out_m = out_w + (size_t)U_UNITS * M_SLOTS;     // memories [64,8192,64]

    float* ws    = (float*)d_ws;
    float* pmax  = ws;                                // U*SCH
    float* psum  = pmax + U_UNITS * SCH;              // U*SCH
    float* pout  = psum + U_UNITS * SCH;              // U*SCH*D

    fused_kernel<<<U_UNITS * SCH, BLK, 0, stream>>>(
        att, atts, tmpr, mask, mem, out_w, out_m, pmax, psum, pout);
    finalize_kernel<<<U_UNITS * WSLICE, BLK, 0, stream>>>(pmax, psum, pout, out_w, out_o);
}